// Round 6
// baseline (582.029 us; speedup 1.0000x reference)
//
#include <hip/hip_runtime.h>

#define E_TOT 500000
#define N_NODES 100000
#define NG_ROWS 256                              // rows per block (2 tiles x 128)
#define NG_BLKH ((N_NODES + NG_ROWS - 1) / NG_ROWS)  // 391

typedef __attribute__((ext_vector_type(16))) float f32x16;
typedef __attribute__((ext_vector_type(8))) short short8;
typedef __attribute__((ext_vector_type(4))) float f32x4;

__device__ __forceinline__ unsigned short f2bf(float f) {
  union { float f; unsigned u; } x; x.f = f;
  unsigned r = x.u + 0x7fffu + ((x.u >> 16) & 1u);
  return (unsigned short)(r >> 16);
}

__device__ __forceinline__ float bf2f(unsigned short s) {
  union { unsigned u; float f; } x; x.u = ((unsigned)s) << 16;
  return x.f;
}

// w1 (f32 [256][512]) -> w1r2 bf16 [half][kseg=0..31][n=0..255][j=0..7]
// k_local = kseg*8 + j  (same layout serves 32x32x16 fragments: kseg = kb*2+hi)
__global__ void k_repack_w1h(const float* __restrict__ w1,
                             unsigned short* __restrict__ w1r2) {
  int o = blockIdx.x * 256 + threadIdx.x;  // 131072 total
  int half = o >> 16;
  int kb = (o >> 11) & 31;
  int n = (o >> 3) & 255;
  int j = o & 7;
  w1r2[o] = f2bf(w1[n * 512 + half * 256 + kb * 8 + j]);
}

// U'[n] = zsrc[n] @ W1s^T + b1 (half 0) ; V[n] = zdst[n] @ W1d^T (half 1)
// Barrier-free, LDS-free: A direct global->reg in MFMA layout, B from L2.
// Wave = 32 rows x 256 cols, K=256 via 16x mfma_f32_32x32x16_bf16 per col-tile.
__global__ __launch_bounds__(256, 3) void k_node_gemm(
    const float* __restrict__ zsrc, const float* __restrict__ zdst,
    const unsigned short* __restrict__ w1r2, const float* __restrict__ b1,
    unsigned short* __restrict__ Uo, unsigned short* __restrict__ Vo) {
  const int bi = blockIdx.x;
  const int half = (bi >= NG_BLKH) ? 1 : 0;
  const int rb0 = (bi - half * NG_BLKH) * NG_ROWS;
  const float* Z = half ? zdst : zsrc;
  unsigned short* O = half ? Vo : Uo;
  const unsigned short* bbase = w1r2 + half * 65536u;

  const unsigned tid = threadIdx.x;
  const unsigned l = tid & 63u;
  const unsigned w = tid >> 6;  // wave 0..3
  const unsigned l31 = l & 31u;
  const unsigned hi = l >> 5;

  float b1v[8];
#pragma unroll
  for (int nf = 0; nf < 8; ++nf)
    b1v[nf] = half ? 0.f : b1[nf * 32 + (int)l31];

  for (int tt = 0; tt < 2; ++tt) {
    const int m0 = rb0 + tt * 128 + (int)w * 32;
    int rr = m0 + (int)l31;
    if (rr > N_NODES - 1) rr = N_NODES - 1;
    // lane reads k = kb*16 + hi*8 + j  (32B contiguous per kb)
    const float* zr = Z + (long)rr * 256 + hi * 8u;

    // ---- A: 16 bf16 fragments, direct from global (no LDS, no barrier) ----
    short8 af[16];
#pragma unroll
    for (int kb = 0; kb < 16; ++kb) {
      f32x4 g0 = ((const f32x4*)(zr + kb * 16))[0];
      f32x4 g1 = ((const f32x4*)(zr + kb * 16))[1];
      short8 sa;
      sa[0] = (short)f2bf(g0.x); sa[1] = (short)f2bf(g0.y);
      sa[2] = (short)f2bf(g0.z); sa[3] = (short)f2bf(g0.w);
      sa[4] = (short)f2bf(g1.x); sa[5] = (short)f2bf(g1.y);
      sa[6] = (short)f2bf(g1.z); sa[7] = (short)f2bf(g1.w);
      af[kb] = sa;
    }

    // ---- col-tiles: B frags streamed from L2, acc stored immediately ----
#pragma unroll
    for (int nf = 0; nf < 8; ++nf) {
      f32x16 acc = {0.f, 0.f, 0.f, 0.f, 0.f, 0.f, 0.f, 0.f,
                    0.f, 0.f, 0.f, 0.f, 0.f, 0.f, 0.f, 0.f};
#pragma unroll
      for (int kb = 0; kb < 16; ++kb) {
        // B frag: lane holds W1[col = nf*32+l31][k = kb*16 + hi*8 + j]
        short8 bf = *(const short8*)(
            bbase + (((unsigned)kb * 2u + hi) * 256u + (unsigned)nf * 32u + l31) * 8u);
        acc = __builtin_amdgcn_mfma_f32_32x32x16_bf16(af[kb], bf, acc, 0, 0, 0);
      }
      // C layout: col = lane&31, row32 = (r&3) + 8*(r>>2) + 4*hi
#pragma unroll
      for (int r = 0; r < 16; ++r) {
        int row32 = (r & 3) + 8 * (r >> 2) + 4 * (int)hi;
        int grow = m0 + row32;
        if (grow < N_NODES)
          O[(long)grow * 256 + nf * 32 + (int)l31] = f2bf(acc[r] + b1v[nf]);
      }
    }
  }
}

// per edge: out = sigmoid( w2 . relu(U'[row] + V[col]) + b2 )
// 3-stage pipeline: idx(e+2) || rows(e+1) || compute(e)
#define EK_ITER 16
__global__ __launch_bounds__(256, 6) void k_edge(
    const unsigned short* __restrict__ U, const unsigned short* __restrict__ V,
    const int* __restrict__ eli, const float* __restrict__ w2,
    const float* __restrict__ b2, float* __restrict__ out) {
  const int tid = threadIdx.x;
  const int g = tid >> 4;
  const int j = tid & 15;
  float w2v[16];
#pragma unroll
  for (int q = 0; q < 8; ++q) {
    w2v[q] = w2[8 * j + q];
    w2v[8 + q] = w2[128 + 8 * j + q];
  }
  const float b2v = b2[0];
  const long base = (long)blockIdx.x * (16 * EK_ITER) + g;

#define CLAMP_E(k) \
  (((base + 16 * (k)) < E_TOT) ? (base + 16 * (k)) : (long)(E_TOT - 1))

  long eP = CLAMP_E(0);
  int rA = eli[eP], cA = eli[E_TOT + eP];
  long eQ = CLAMP_E(1);
  int rB = eli[eQ], cB = eli[E_TOT + eQ];
  short8 uA0 = *(const short8*)(U + (long)rA * 256 + 8 * j);
  short8 uA1 = *(const short8*)(U + (long)rA * 256 + 128 + 8 * j);
  short8 vA0 = *(const short8*)(V + (long)cA * 256 + 8 * j);
  short8 vA1 = *(const short8*)(V + (long)cA * 256 + 128 + 8 * j);
  short8 uB0, uB1, vB0, vB1;

#pragma unroll
  for (int it2 = 0; it2 < EK_ITER / 2; ++it2) {
    {
      long eN = CLAMP_E(2 * it2 + 2);
      int rN = eli[eN], cN = eli[E_TOT + eN];
      uB0 = *(const short8*)(U + (long)rB * 256 + 8 * j);
      uB1 = *(const short8*)(U + (long)rB * 256 + 128 + 8 * j);
      vB0 = *(const short8*)(V + (long)cB * 256 + 8 * j);
      vB1 = *(const short8*)(V + (long)cB * 256 + 128 + 8 * j);
      rB = rN; cB = cN;
      float p = 0.f;
#pragma unroll
      for (int q = 0; q < 8; ++q) {
        float a0 = bf2f((unsigned short)uA0[q]) + bf2f((unsigned short)vA0[q]);
        float a1 = bf2f((unsigned short)uA1[q]) + bf2f((unsigned short)vA1[q]);
        p = fmaf(fmaxf(a0, 0.f), w2v[q], p);
        p = fmaf(fmaxf(a1, 0.f), w2v[8 + q], p);
      }
      p += __shfl_xor(p, 1);
      p += __shfl_xor(p, 2);
      p += __shfl_xor(p, 4);
      p += __shfl_xor(p, 8);
      long e = base + 16 * (2 * it2);
      if (j == 0 && e < E_TOT) out[e] = 1.f / (1.f + __expf(-(p + b2v)));
    }
    {
      long eN = CLAMP_E(2 * it2 + 3);
      int rN = eli[eN], cN = eli[E_TOT + eN];
      uA0 = *(const short8*)(U + (long)rB * 256 + 8 * j);
      uA1 = *(const short8*)(U + (long)rB * 256 + 128 + 8 * j);
      vA0 = *(const short8*)(V + (long)cB * 256 + 8 * j);
      vA1 = *(const short8*)(V + (long)cB * 256 + 128 + 8 * j);
      rB = rN; cB = cN;
      float p = 0.f;
#pragma unroll
      for (int q = 0; q < 8; ++q) {
        float a0 = bf2f((unsigned short)uB0[q]) + bf2f((unsigned short)vB0[q]);
        float a1 = bf2f((unsigned short)uB1[q]) + bf2f((unsigned short)vB1[q]);
        p = fmaf(fmaxf(a0, 0.f), w2v[q], p);
        p = fmaf(fmaxf(a1, 0.f), w2v[8 + q], p);
      }
      p += __shfl_xor(p, 1);
      p += __shfl_xor(p, 2);
      p += __shfl_xor(p, 4);
      p += __shfl_xor(p, 8);
      long e = base + 16 * (2 * it2 + 1);
      if (j == 0 && e < E_TOT) out[e] = 1.f / (1.f + __expf(-(p + b2v)));
    }
  }
#undef CLAMP_E
}

extern "C" void kernel_launch(void* const* d_in, const int* in_sizes, int n_in,
                              void* d_out, int out_size, void* d_ws,
                              size_t ws_size, hipStream_t stream) {
  const float* zsrc = (const float*)d_in[0];
  const float* zdst = (const float*)d_in[1];
  const int* eli = (const int*)d_in[2];
  const float* w1 = (const float*)d_in[3];
  const float* b1 = (const float*)d_in[4];
  const float* w2 = (const float*)d_in[5];
  const float* b2 = (const float*)d_in[6];
  float* out = (float*)d_out;

  const size_t uv_bytes = (size_t)N_NODES * 256 * 2;  // 51.2 MB each
  unsigned short* U = (unsigned short*)d_ws;
  unsigned short* V = (unsigned short*)((char*)d_ws + uv_bytes);
  unsigned short* w1r2 = (unsigned short*)((char*)d_ws + 2 * uv_bytes);

  k_repack_w1h<<<512, 256, 0, stream>>>(w1, w1r2);
  k_node_gemm<<<2 * NG_BLKH, 256, 0, stream>>>(zsrc, zdst, w1r2, b1, U, V);
  int nbe = (E_TOT + 16 * EK_ITER - 1) / (16 * EK_ITER);
  k_edge<<<nbe, 256, 0, stream>>>(U, V, eli, w2, b2, out);
}

// Round 7
// 181.413 us; speedup vs baseline: 3.2083x; 3.2083x over previous
//
#include <hip/hip_runtime.h>

#define E_TOT 500000
#define N_NODES 100000
#define RB 128
#define NBH2 ((N_NODES + RB - 1) / RB)  // 782 row-blocks per half
#define CSTR 264

typedef __attribute__((ext_vector_type(16))) float f32x16;
typedef __attribute__((ext_vector_type(8))) short short8;
typedef __attribute__((ext_vector_type(4))) float f32x4;

__device__ __forceinline__ unsigned short f2bf(float f) {
  union { float f; unsigned u; } x; x.f = f;
  unsigned r = x.u + 0x7fffu + ((x.u >> 16) & 1u);
  return (unsigned short)(r >> 16);
}

__device__ __forceinline__ float bf2f(unsigned short s) {
  union { unsigned u; float f; } x; x.u = ((unsigned)s) << 16;
  return x.f;
}

__device__ __forceinline__ void gl_lds16(const void* g, void* l) {
  __builtin_amdgcn_global_load_lds(
      (const __attribute__((address_space(1))) void*)g,
      (__attribute__((address_space(3))) void*)l, 16, 0, 0);
}

// w1 (f32 [256][512]) -> w1r2 bf16 [half][kseg=0..31][n=0..255][j=0..7]
__global__ void k_repack_w1h(const float* __restrict__ w1,
                             unsigned short* __restrict__ w1r2) {
  int o = blockIdx.x * 256 + threadIdx.x;  // 131072 total
  int half = o >> 16;
  int kb = (o >> 11) & 31;
  int n = (o >> 3) & 255;
  int j = o & 7;
  w1r2[o] = f2bf(w1[n * 512 + half * 256 + kb * 8 + j]);
}

// U'[n] = zsrc[n] @ W1s^T + b1 (half 0) ; V[n] = zdst[n] @ W1d^T (half 1)
// v7: B LDS double-buffered (staged once/chunk/block), A direct global->frag,
// 2-phase pipeline: one barrier per chunk, next-chunk loads fly under MFMA.
__global__ __launch_bounds__(512, 2) void k_node_gemm(
    const float* __restrict__ zsrc, const float* __restrict__ zdst,
    const unsigned short* __restrict__ w1r2, const float* __restrict__ b1,
    unsigned short* __restrict__ Uo, unsigned short* __restrict__ Vo) {
  __shared__ __align__(16) char smem[RB * CSTR * 2];  // 67584 B
  unsigned short* Bb[2] = {(unsigned short*)smem,
                           (unsigned short*)(smem + 32768)};
  unsigned short* C_lds = (unsigned short*)smem;  // epilogue overlay

  const int bi = blockIdx.x;
  const int half = (bi >= NBH2) ? 1 : 0;
  const int rb0 = (bi - half * NBH2) * RB;
  const float* Z = half ? zdst : zsrc;
  unsigned short* O = half ? Vo : Uo;
  const unsigned short* bbase = w1r2 + half * 65536u;

  const unsigned tid = threadIdx.x;
  const unsigned l = tid & 63u;
  const unsigned w = tid >> 6;   // 8 waves: wr = w&3 (rows), wc = w>>2 (cols)
  const unsigned wr = w & 3u;
  const unsigned wc = w >> 2;
  const unsigned l31 = l & 31u;
  const unsigned hi = l >> 5;

  // A row for this lane (32 rows per wave-row-group)
  int rr = rb0 + (int)wr * 32 + (int)l31;
  if (rr > N_NODES - 1) rr = N_NODES - 1;
  const float* zr = Z + (long)rr * 256 + hi * 8u;

  // B stage helper: chunk c -> buffer b (32 KB linear)
#define STAGE_B(c, b)                                              \
  {                                                                \
    const unsigned short* bs = bbase + (unsigned)(c) * 16384u;     \
    unsigned short* bd = Bb[b];                                    \
    _Pragma("unroll") for (int q = 0; q < 4; ++q) {                \
      unsigned off = (w * 4u + (unsigned)q) * 512u;                \
      gl_lds16(bs + off + l * 8u, bd + off);                       \
    }                                                              \
  }

// A frags for chunk c into fr[4] (direct global, coalesced 32B/lane granules)
#define LOAD_A(c, fr)                                              \
  _Pragma("unroll") for (int kb = 0; kb < 4; ++kb) {               \
    const float* g = zr + (c) * 64 + kb * 16;                      \
    f32x4 g0 = ((const f32x4*)g)[0];                               \
    f32x4 g1 = ((const f32x4*)g)[1];                               \
    short8 sa;                                                     \
    sa[0] = (short)f2bf(g0.x); sa[1] = (short)f2bf(g0.y);          \
    sa[2] = (short)f2bf(g0.z); sa[3] = (short)f2bf(g0.w);          \
    sa[4] = (short)f2bf(g1.x); sa[5] = (short)f2bf(g1.y);          \
    sa[6] = (short)f2bf(g1.z); sa[7] = (short)f2bf(g1.w);          \
    (fr)[kb] = sa;                                                 \
  }

  f32x16 acc[4];
#pragma unroll
  for (int nf = 0; nf < 4; ++nf)
    acc[nf] = (f32x16){0.f, 0.f, 0.f, 0.f, 0.f, 0.f, 0.f, 0.f,
                       0.f, 0.f, 0.f, 0.f, 0.f, 0.f, 0.f, 0.f};

  short8 afA[4], afB[4];

  // prologue: stage chunk 0 + A(0)
  STAGE_B(0, 0);
  LOAD_A(0, afA);

#pragma unroll
  for (int c = 0; c < 4; ++c) {
    __syncthreads();  // drains stage(c) vmem -> Bb[c&1] valid

    if (c < 3) {      // issue next chunk NOW; flies under MFMA(c)
      STAGE_B(c + 1, (c + 1) & 1);
      if (c & 1) { LOAD_A(c + 1, afA); } else { LOAD_A(c + 1, afB); }
    }

    const unsigned short* Bcur = Bb[c & 1];
    const short8* afc = (c & 1) ? afB : afA;
#pragma unroll
    for (int nf = 0; nf < 4; ++nf) {
#pragma unroll
      for (int kb = 0; kb < 4; ++kb) {
        // kseg_local = kb*2+hi ; col = wc*128 + nf*32 + l31
        short8 bf = *(const short8*)(
            Bcur +
            (((unsigned)kb * 2u + hi) * 256u + wc * 128u + (unsigned)nf * 32u + l31) * 8u);
        acc[nf] = __builtin_amdgcn_mfma_f32_32x32x16_bf16(afc[kb], bf, acc[nf], 0, 0, 0);
      }
    }
  }
#undef STAGE_B
#undef LOAD_A

  // ---- epilogue: bias, cast, LDS transpose, coalesced 16B stores ----
  float b1v[4];
#pragma unroll
  for (int nf = 0; nf < 4; ++nf)
    b1v[nf] = half ? 0.f : b1[wc * 128u + nf * 32 + l31];

  __syncthreads();  // all B reads done -> overlay C
#pragma unroll
  for (int nf = 0; nf < 4; ++nf) {
#pragma unroll
    for (int r = 0; r < 16; ++r) {
      unsigned row32 = (unsigned)((r & 3) + 8 * (r >> 2)) + 4u * hi;
      unsigned row = wr * 32u + row32;
      unsigned col = wc * 128u + (unsigned)nf * 32u + l31;
      C_lds[row * CSTR + col] = f2bf(acc[nf][r] + b1v[nf]);
    }
  }
  __syncthreads();
#pragma unroll
  for (int k = 0; k < 8; ++k) {
    unsigned u = tid + (unsigned)k * 512u;
    unsigned row = u >> 5;
    unsigned cu = u & 31u;
    if (rb0 + (int)row < N_NODES) {
      short8 vv = *(const short8*)&C_lds[row * CSTR + cu * 8u];
      *(short8*)(O + (long)(rb0 + row) * 256 + cu * 8u) = vv;
    }
  }
}

// per edge: out = sigmoid( w2 . relu(U'[row] + V[col]) + b2 )
#define EK_ITER 16
__global__ __launch_bounds__(256, 6) void k_edge(
    const unsigned short* __restrict__ U, const unsigned short* __restrict__ V,
    const int* __restrict__ eli, const float* __restrict__ w2,
    const float* __restrict__ b2, float* __restrict__ out) {
  const int tid = threadIdx.x;
  const int g = tid >> 4;
  const int j = tid & 15;
  float w2v[16];
#pragma unroll
  for (int q = 0; q < 8; ++q) {
    w2v[q] = w2[8 * j + q];
    w2v[8 + q] = w2[128 + 8 * j + q];
  }
  const float b2v = b2[0];
  const long base = (long)blockIdx.x * (16 * EK_ITER) + g;

#define CLAMP_E(k) \
  (((base + 16 * (k)) < E_TOT) ? (base + 16 * (k)) : (long)(E_TOT - 1))

  long eP = CLAMP_E(0);
  int rA = eli[eP], cA = eli[E_TOT + eP];
  long eQ = CLAMP_E(1);
  int rB = eli[eQ], cB = eli[E_TOT + eQ];
  short8 uA0 = *(const short8*)(U + (long)rA * 256 + 8 * j);
  short8 uA1 = *(const short8*)(U + (long)rA * 256 + 128 + 8 * j);
  short8 vA0 = *(const short8*)(V + (long)cA * 256 + 8 * j);
  short8 vA1 = *(const short8*)(V + (long)cA * 256 + 128 + 8 * j);
  short8 uB0, uB1, vB0, vB1;

#pragma unroll
  for (int it2 = 0; it2 < EK_ITER / 2; ++it2) {
    {
      long eN = CLAMP_E(2 * it2 + 2);
      int rN = eli[eN], cN = eli[E_TOT + eN];
      uB0 = *(const short8*)(U + (long)rB * 256 + 8 * j);
      uB1 = *(const short8*)(U + (long)rB * 256 + 128 + 8 * j);
      vB0 = *(const short8*)(V + (long)cB * 256 + 8 * j);
      vB1 = *(const short8*)(V + (long)cB * 256 + 128 + 8 * j);
      rB = rN; cB = cN;
      float p = 0.f;
#pragma unroll
      for (int q = 0; q < 8; ++q) {
        float a0 = bf2f((unsigned short)uA0[q]) + bf2f((unsigned short)vA0[q]);
        float a1 = bf2f((unsigned short)uA1[q]) + bf2f((unsigned short)vA1[q]);
        p = fmaf(fmaxf(a0, 0.f), w2v[q], p);
        p = fmaf(fmaxf(a1, 0.f), w2v[8 + q], p);
      }
      p += __shfl_xor(p, 1);
      p += __shfl_xor(p, 2);
      p += __shfl_xor(p, 4);
      p += __shfl_xor(p, 8);
      long e = base + 16 * (2 * it2);
      if (j == 0 && e < E_TOT) out[e] = 1.f / (1.f + __expf(-(p + b2v)));
    }
    {
      long eN = CLAMP_E(2 * it2 + 3);
      int rN = eli[eN], cN = eli[E_TOT + eN];
      uA0 = *(const short8*)(U + (long)rB * 256 + 8 * j);
      uA1 = *(const short8*)(U + (long)rB * 256 + 128 + 8 * j);
      vA0 = *(const short8*)(V + (long)cB * 256 + 8 * j);
      vA1 = *(const short8*)(V + (long)cB * 256 + 128 + 8 * j);
      rB = rN; cB = cN;
      float p = 0.f;
#pragma unroll
      for (int q = 0; q < 8; ++q) {
        float a0 = bf2f((unsigned short)uB0[q]) + bf2f((unsigned short)vB0[q]);
        float a1 = bf2f((unsigned short)uB1[q]) + bf2f((unsigned short)vB1[q]);
        p = fmaf(fmaxf(a0, 0.f), w2v[q], p);
        p = fmaf(fmaxf(a1, 0.f), w2v[8 + q], p);
      }
      p += __shfl_xor(p, 1);
      p += __shfl_xor(p, 2);
      p += __shfl_xor(p, 4);
      p += __shfl_xor(p, 8);
      long e = base + 16 * (2 * it2 + 1);
      if (j == 0 && e < E_TOT) out[e] = 1.f / (1.f + __expf(-(p + b2v)));
    }
  }
#undef CLAMP_E
}

extern "C" void kernel_launch(void* const* d_in, const int* in_sizes, int n_in,
                              void* d_out, int out_size, void* d_ws,
                              size_t ws_size, hipStream_t stream) {
  const float* zsrc = (const float*)d_in[0];
  const float* zdst = (const float*)d_in[1];
  const int* eli = (const int*)d_in[2];
  const float* w1 = (const float*)d_in[3];
  const float* b1 = (const float*)d_in[4];
  const float* w2 = (const float*)d_in[5];
  const float* b2 = (const float*)d_in[6];
  float* out = (float*)d_out;

  const size_t uv_bytes = (size_t)N_NODES * 256 * 2;  // 51.2 MB each
  unsigned short* U = (unsigned short*)d_ws;
  unsigned short* V = (unsigned short*)((char*)d_ws + uv_bytes);
  unsigned short* w1r2 = (unsigned short*)((char*)d_ws + 2 * uv_bytes);

  k_repack_w1h<<<512, 256, 0, stream>>>(w1, w1r2);
  k_node_gemm<<<2 * NBH2, 512, 0, stream>>>(zsrc, zdst, w1r2, b1, U, V);
  int nbe = (E_TOT + 16 * EK_ITER - 1) / (16 * EK_ITER);
  k_edge<<<nbe, 256, 0, stream>>>(U, V, eli, w2, b2, out);
}

// Round 8
// 180.138 us; speedup vs baseline: 3.2310x; 1.0071x over previous
//
#include <hip/hip_runtime.h>

#define E_TOT 500000
#define N_NODES 100000
#define RB 128
#define NBH2 ((N_NODES + RB - 1) / RB)  // 782 row-blocks per half

typedef __attribute__((ext_vector_type(16))) float f32x16;
typedef __attribute__((ext_vector_type(8))) short short8;
typedef __attribute__((ext_vector_type(4))) float f32x4;

__device__ __forceinline__ unsigned short f2bf(float f) {
  union { float f; unsigned u; } x; x.f = f;
  unsigned r = x.u + 0x7fffu + ((x.u >> 16) & 1u);
  return (unsigned short)(r >> 16);
}

__device__ __forceinline__ float bf2f(unsigned short s) {
  union { unsigned u; float f; } x; x.u = ((unsigned)s) << 16;
  return x.f;
}

// w1 (f32 [256][512]) -> w1r2 bf16 [half][kseg=0..31][n=0..255][j=0..7]
__global__ void k_repack_w1h(const float* __restrict__ w1,
                             unsigned short* __restrict__ w1r2) {
  int o = blockIdx.x * 256 + threadIdx.x;  // 131072 total
  int half = o >> 16;
  int kb = (o >> 11) & 31;
  int n = (o >> 3) & 255;
  int j = o & 7;
  w1r2[o] = f2bf(w1[n * 512 + half * 256 + kb * 8 + j]);
}

// U'[n] = zsrc[n] @ W1s^T + b1 (half 0) ; V[n] = zdst[n] @ W1d^T (half 1)
// v8: barrier-free per-wave compute (A global->frag once, B streamed from L2),
// epilogue per 64-col pair via small LDS tile -> 128B full-line stores.
__global__ __launch_bounds__(256, 3) void k_node_gemm(
    const float* __restrict__ zsrc, const float* __restrict__ zdst,
    const unsigned short* __restrict__ w1r2, const float* __restrict__ b1,
    unsigned short* __restrict__ Uo, unsigned short* __restrict__ Vo) {
  __shared__ __align__(16) unsigned short Tl[RB][68];  // 17408 B

  const int bi = blockIdx.x;
  const int half = (bi >= NBH2) ? 1 : 0;
  const int rb0 = (bi - half * NBH2) * RB;
  const float* Z = half ? zdst : zsrc;
  unsigned short* O = half ? Vo : Uo;
  const unsigned short* bbase = w1r2 + half * 65536u;

  const unsigned tid = threadIdx.x;
  const unsigned l = tid & 63u;
  const unsigned w = tid >> 6;  // wave 0..3 -> rows w*32..w*32+31
  const unsigned l31 = l & 31u;
  const unsigned hi = l >> 5;

  // ---- A: 16 bf16 fragments, direct from global, read ONCE ----
  int rr = rb0 + (int)w * 32 + (int)l31;
  if (rr > N_NODES - 1) rr = N_NODES - 1;
  const float* zr = Z + (long)rr * 256 + hi * 8u;

  short8 af[16];
#pragma unroll
  for (int kb = 0; kb < 16; ++kb) {
    f32x4 g0 = ((const f32x4*)(zr + kb * 16))[0];
    f32x4 g1 = ((const f32x4*)(zr + kb * 16))[1];
    short8 sa;
    sa[0] = (short)f2bf(g0.x); sa[1] = (short)f2bf(g0.y);
    sa[2] = (short)f2bf(g0.z); sa[3] = (short)f2bf(g0.w);
    sa[4] = (short)f2bf(g1.x); sa[5] = (short)f2bf(g1.y);
    sa[6] = (short)f2bf(g1.z); sa[7] = (short)f2bf(g1.w);
    af[kb] = sa;
  }

  // ---- 4 col-pairs of 64 cols each ----
#pragma unroll 1
  for (int np = 0; np < 4; ++np) {
    f32x16 acc0 = {0.f, 0.f, 0.f, 0.f, 0.f, 0.f, 0.f, 0.f,
                   0.f, 0.f, 0.f, 0.f, 0.f, 0.f, 0.f, 0.f};
    f32x16 acc1 = acc0;
#pragma unroll
    for (int kb = 0; kb < 16; ++kb) {
      const unsigned short* bp =
          bbase + (((unsigned)kb * 2u + hi) * 256u + (unsigned)np * 64u + l31) * 8u;
      short8 b0 = *(const short8*)bp;
      short8 b1f = *(const short8*)(bp + 256);  // +32 cols * 8
      acc0 = __builtin_amdgcn_mfma_f32_32x32x16_bf16(af[kb], b0, acc0, 0, 0, 0);
      acc1 = __builtin_amdgcn_mfma_f32_32x32x16_bf16(af[kb], b1f, acc1, 0, 0, 0);
    }
    float bia0 = half ? 0.f : b1[np * 64 + (int)l31];
    float bia1 = half ? 0.f : b1[np * 64 + 32 + (int)l31];

    // stage 128x64 tile: lane writes col l31 / l31+32 of its 16 rows
#pragma unroll
    for (int r = 0; r < 16; ++r) {
      unsigned row32 = (unsigned)((r & 3) + 8 * (r >> 2)) + 4u * hi;
      unsigned row = w * 32u + row32;
      Tl[row][l31] = f2bf(acc0[r] + bia0);
      Tl[row][32u + l31] = f2bf(acc1[r] + bia1);
    }
    __syncthreads();
    // store: 8 lanes x 16B = 128B contiguous per row (full line)
#pragma unroll
    for (int t = 0; t < 2; ++t) {
      unsigned s = (unsigned)t * 256u + tid;
      unsigned row = s >> 3;
      unsigned seg = s & 7u;
      if (rb0 + (int)row < N_NODES) {
        short8 vv = *(const short8*)&Tl[row][seg * 8u];
        *(short8*)(O + (long)(rb0 + row) * 256 + np * 64 + seg * 8u) = vv;
      }
      s += 512u;
      row = s >> 3;
      seg = s & 7u;
      if (rb0 + (int)row < N_NODES) {
        short8 vv = *(const short8*)&Tl[row][seg * 8u];
        *(short8*)(O + (long)(rb0 + row) * 256 + np * 64 + seg * 8u) = vv;
      }
    }
    __syncthreads();
  }
}

// per edge: out = sigmoid( w2 . relu(U'[row] + V[col]) + b2 )
// 3-stage pipeline: idx(e+2) || rows(e+1) || compute(e)
#define EK_ITER 16
__global__ __launch_bounds__(256, 6) void k_edge(
    const unsigned short* __restrict__ U, const unsigned short* __restrict__ V,
    const int* __restrict__ eli, const float* __restrict__ w2,
    const float* __restrict__ b2, float* __restrict__ out) {
  const int tid = threadIdx.x;
  const int g = tid >> 4;
  const int j = tid & 15;
  float w2v[16];
#pragma unroll
  for (int q = 0; q < 8; ++q) {
    w2v[q] = w2[8 * j + q];
    w2v[8 + q] = w2[128 + 8 * j + q];
  }
  const float b2v = b2[0];
  const long base = (long)blockIdx.x * (16 * EK_ITER) + g;

#define CLAMP_E(k) \
  (((base + 16 * (k)) < E_TOT) ? (base + 16 * (k)) : (long)(E_TOT - 1))

  long eP = CLAMP_E(0);
  int rA = eli[eP], cA = eli[E_TOT + eP];
  long eQ = CLAMP_E(1);
  int rB = eli[eQ], cB = eli[E_TOT + eQ];
  short8 uA0 = *(const short8*)(U + (long)rA * 256 + 8 * j);
  short8 uA1 = *(const short8*)(U + (long)rA * 256 + 128 + 8 * j);
  short8 vA0 = *(const short8*)(V + (long)cA * 256 + 8 * j);
  short8 vA1 = *(const short8*)(V + (long)cA * 256 + 128 + 8 * j);
  short8 uB0, uB1, vB0, vB1;

#pragma unroll
  for (int it2 = 0; it2 < EK_ITER / 2; ++it2) {
    {
      long eN = CLAMP_E(2 * it2 + 2);
      int rN = eli[eN], cN = eli[E_TOT + eN];
      uB0 = *(const short8*)(U + (long)rB * 256 + 8 * j);
      uB1 = *(const short8*)(U + (long)rB * 256 + 128 + 8 * j);
      vB0 = *(const short8*)(V + (long)cB * 256 + 8 * j);
      vB1 = *(const short8*)(V + (long)cB * 256 + 128 + 8 * j);
      rB = rN; cB = cN;
      float p = 0.f;
#pragma unroll
      for (int q = 0; q < 8; ++q) {
        float a0 = bf2f((unsigned short)uA0[q]) + bf2f((unsigned short)vA0[q]);
        float a1 = bf2f((unsigned short)uA1[q]) + bf2f((unsigned short)vA1[q]);
        p = fmaf(fmaxf(a0, 0.f), w2v[q], p);
        p = fmaf(fmaxf(a1, 0.f), w2v[8 + q], p);
      }
      p += __shfl_xor(p, 1);
      p += __shfl_xor(p, 2);
      p += __shfl_xor(p, 4);
      p += __shfl_xor(p, 8);
      long e = base + 16 * (2 * it2);
      if (j == 0 && e < E_TOT) out[e] = 1.f / (1.f + __expf(-(p + b2v)));
    }
    {
      long eN = CLAMP_E(2 * it2 + 3);
      int rN = eli[eN], cN = eli[E_TOT + eN];
      uA0 = *(const short8*)(U + (long)rB * 256 + 8 * j);
      uA1 = *(const short8*)(U + (long)rB * 256 + 128 + 8 * j);
      vA0 = *(const short8*)(V + (long)cB * 256 + 8 * j);
      vA1 = *(const short8*)(V + (long)cB * 256 + 128 + 8 * j);
      rB = rN; cB = cN;
      float p = 0.f;
#pragma unroll
      for (int q = 0; q < 8; ++q) {
        float a0 = bf2f((unsigned short)uB0[q]) + bf2f((unsigned short)vB0[q]);
        float a1 = bf2f((unsigned short)uB1[q]) + bf2f((unsigned short)vB1[q]);
        p = fmaf(fmaxf(a0, 0.f), w2v[q], p);
        p = fmaf(fmaxf(a1, 0.f), w2v[8 + q], p);
      }
      p += __shfl_xor(p, 1);
      p += __shfl_xor(p, 2);
      p += __shfl_xor(p, 4);
      p += __shfl_xor(p, 8);
      long e = base + 16 * (2 * it2 + 1);
      if (j == 0 && e < E_TOT) out[e] = 1.f / (1.f + __expf(-(p + b2v)));
    }
  }
#undef CLAMP_E
}

extern "C" void kernel_launch(void* const* d_in, const int* in_sizes, int n_in,
                              void* d_out, int out_size, void* d_ws,
                              size_t ws_size, hipStream_t stream) {
  const float* zsrc = (const float*)d_in[0];
  const float* zdst = (const float*)d_in[1];
  const int* eli = (const int*)d_in[2];
  const float* w1 = (const float*)d_in[3];
  const float* b1 = (const float*)d_in[4];
  const float* w2 = (const float*)d_in[5];
  const float* b2 = (const float*)d_in[6];
  float* out = (float*)d_out;

  const size_t uv_bytes = (size_t)N_NODES * 256 * 2;  // 51.2 MB each
  unsigned short* U = (unsigned short*)d_ws;
  unsigned short* V = (unsigned short*)((char*)d_ws + uv_bytes);
  unsigned short* w1r2 = (unsigned short*)((char*)d_ws + 2 * uv_bytes);

  k_repack_w1h<<<512, 256, 0, stream>>>(w1, w1r2);
  k_node_gemm<<<2 * NBH2, 256, 0, stream>>>(zsrc, zdst, w1r2, b1, U, V);
  int nbe = (E_TOT + 16 * EK_ITER - 1) / (16 * EK_ITER);
  k_edge<<<nbe, 256, 0, stream>>>(U, V, eli, w2, b2, out);
}